// Round 10
// baseline (136.381 us; speedup 1.0000x reference)
//
#include <hip/hip_runtime.h>
#include <math.h>

#define BB 256
#define LL 8
#define DD 200
#define NN 100000
#define BN 32                        // concepts per tile (100000 % 32 == 0)
#define NTILE (NN / BN)              // 3125
#define NGRAN 28                     // 16B bf16 granules per row (K padded to 224)
#define GRIDN 512                    // grid size == co-resident capacity (2/CU x 256)
#define NCAND 6

typedef __attribute__((ext_vector_type(8))) __bf16 bf16x8;
typedef __attribute__((ext_vector_type(16))) float f32x16;

// fp32 -> bf16 round-to-nearest-even
__device__ __forceinline__ unsigned f2bf(float x) {
  unsigned u = __float_as_uint(x);
  u = (u + 0x7fffu + ((u >> 16) & 1u)) >> 16;
  return u;
}
__device__ __forceinline__ unsigned pk(float a, float b) {
  return f2bf(a) | (f2bf(b) << 16);
}
// numpy argmax semantics: larger wins; exact tie -> smaller index
__device__ __forceinline__ bool better(float a, int ia, float b, int ib) {
  return (a > b) || (a == b && ia < ib);
}
__device__ __forceinline__ float dot4(float4 f) {
  return f.x * f.x + f.y * f.y + f.z * f.z + f.w * f.w;
}

// Single fused kernel; ordering via device-scope atomics (no cooperative API
// -- fails under graph capture, R7). Co-residency of all 512 blocks is by
// construction: LDS 29.7KB + VGPR<=128 -> 2 blocks/CU x 256 CU = 512.
// R9 lesson: launch_bounds(512,4) only sets the VGPR *cap*; the allocator
// targeted 8 waves/EU (64 VGPR) and spilled areg into a per-tile L2 reload
// chain (135us, 85% idle). amdgpu_waves_per_eu(4,4) pins the occupancy
// target to what LDS already limits us to, freeing the full 128-reg budget.
__attribute__((amdgpu_waves_per_eu(4, 4)))
__global__ void __launch_bounds__(512, 4) fused_kernel(
    const int* __restrict__ ids, const float* __restrict__ we,
    const float* __restrict__ dict, unsigned short* __restrict__ abf,
    float* __restrict__ repf, float* __restrict__ mnorm,
    float4* __restrict__ partial, float* __restrict__ out,
    int* __restrict__ ctr) {
  __shared__ uint4 Bs[2][NGRAN * BN];   // 2 x 14 KB ring (phase B)
  __shared__ float redA[8];             // phase A
  __shared__ float repL[DD];            // phase C
  __shared__ float wv[8];  __shared__ int wi[8];
  __shared__ int seln[NCAND];
  __shared__ float finv[NCAND]; __shared__ int finn[NCAND];

  const int tid = threadIdx.x;

  // staging roles (phase B), also used for zero-pad below
  int row = tid >> 4, part = tid & 15;
  const bool extra = (part < 2);
  int g0i = part >> 1, h = part & 1;

  // zero-pad granules 25..27 (k 200..223) once, both buffers
  if (tid < 192) {
    int buf = tid / 96, u = tid % 96;
    int g = 25 + u / 32, r = u & 31;
    Bs[buf][g * 32 + (r ^ (g & 7))] = make_uint4(0, 0, 0, 0);
  }

  // ================= Phase A: mention reps (blocks 0..255) ==============
  if (blockIdx.x < BB) {
    int mm = blockIdx.x, d = tid;
    float r = 0.f;
    if (d < DD) {
      int base = mm * LL;
#pragma unroll
      for (int l2 = 0; l2 < LL; ++l2) r += we[(size_t)ids[base + l2] * DD + d];
      r *= 0.125f;
      repf[mm * DD + d] = r;
    }
    if (d < NGRAN * 8) {
      int g = d >> 3, wo = d & 7;
      abf[(g * 256 + mm) * 8 + wo] = (unsigned short)f2bf(d < DD ? r : 0.f);
    }
    float sq = (d < DD) ? r * r : 0.f;
#pragma unroll
    for (int off = 32; off; off >>= 1) sq += __shfl_down(sq, off);
    if ((tid & 63) == 0) redA[tid >> 6] = sq;
    __syncthreads();
    if (tid == 0) {
      float s = 0.f;
#pragma unroll
      for (int q = 0; q < 8; ++q) s += redA[q];
      mnorm[blockIdx.x] = sqrtf(s);
    }
    __syncthreads();   // all abf/repf stores of this block retired
    if (tid == 0)
      __hip_atomic_fetch_add(&ctr[0], 1, __ATOMIC_RELEASE,
                             __HIP_MEMORY_SCOPE_AGENT);
  }

  // ================= Phase B: fused convert + MFMA sims ==================
  {
    int w = tid >> 6, l = tid & 63;
    int ln = l & 31, kh = l >> 5;
    int bm = w * 32 + ln;
    const uint4* abfT = (const uint4*)abf;

    float v1 = -INFINITY, v2 = -INFINITY;
    int i1 = 0x7fffffff, i2 = 0x7fffffff;

    int t0 = blockIdx.x;
    {  // prologue: stage tile t0 into buf 0 (independent of phase A)
      const float* src = dict + (size_t)(t0 * BN + row) * DD;
      float4 f0 = *(const float4*)(src + 4 * part);
      float4 f1 = *(const float4*)(src + 64 + 4 * part);
      float4 f2 = *(const float4*)(src + 128 + 4 * part);
      float4 f3 = extra ? *(const float4*)(src + 192 + 4 * part)
                        : make_float4(0.f, 0.f, 0.f, 0.f);
      float sq = dot4(f0) + dot4(f1) + dot4(f2) + dot4(f3);
      sq += __shfl_xor(sq, 1); sq += __shfl_xor(sq, 2);
      sq += __shfl_xor(sq, 4); sq += __shfl_xor(sq, 8);
      float rs = 1.0f / fmaxf(sqrtf(sq), 1e-8f);
      uint2* B2 = (uint2*)&Bs[0][0];
      B2[(g0i * 32 + (row ^ (g0i & 7))) * 2 + h] =
          make_uint2(pk(f0.x * rs, f0.y * rs), pk(f0.z * rs, f0.w * rs));
      int ga = 8 + g0i;
      B2[(ga * 32 + (row ^ (ga & 7))) * 2 + h] =
          make_uint2(pk(f1.x * rs, f1.y * rs), pk(f1.z * rs, f1.w * rs));
      int gb = 16 + g0i;
      B2[(gb * 32 + (row ^ (gb & 7))) * 2 + h] =
          make_uint2(pk(f2.x * rs, f2.y * rs), pk(f2.z * rs, f2.w * rs));
      if (extra)
        B2[(24 * 32 + row) * 2 + part] =
            make_uint2(pk(f3.x * rs, f3.y * rs), pk(f3.z * rs, f3.w * rs));
    }

    // wait for ALL prep blocks, then load mention fragments
    if (tid == 0) {
      while (__hip_atomic_load(&ctr[0], __ATOMIC_ACQUIRE,
                               __HIP_MEMORY_SCOPE_AGENT) < BB)
        __builtin_amdgcn_s_sleep(2);
    }
    __syncthreads();   // covers prologue LDS writes AND the acquire

    uint4 areg[14];
#pragma unroll
    for (int j = 0; j < 14; ++j) areg[j] = abfT[(2 * j + kh) * 256 + bm];
    // Pin fragments in VGPRs: opaque defs the compiler cannot rematerialize.
#pragma unroll
    for (int j = 0; j < 14; ++j)
      asm volatile("" : "+v"(areg[j].x), "+v"(areg[j].y),
                        "+v"(areg[j].z), "+v"(areg[j].w));

    int cur = 0;
    for (int t = t0; t < NTILE; t += GRIDN) {
      bool hn = (t + GRIDN) < NTILE;
      float4 f0, f1, f2, f3;
      if (hn) {  // issue next tile's loads early (hide under MFMA+scan)
        const float* src = dict + (size_t)((t + GRIDN) * BN + row) * DD;
        f0 = *(const float4*)(src + 4 * part);
        f1 = *(const float4*)(src + 64 + 4 * part);
        f2 = *(const float4*)(src + 128 + 4 * part);
        f3 = extra ? *(const float4*)(src + 192 + 4 * part)
                   : make_float4(0.f, 0.f, 0.f, 0.f);
      }
      __builtin_amdgcn_sched_barrier(0);   // keep loads issued here

      f32x16 acc;
#pragma unroll
      for (int i = 0; i < 16; ++i) acc[i] = 0.f;
      const uint4* B = Bs[cur];
#pragma unroll
      for (int j = 0; j < 14; ++j) {
        int g = 2 * j + kh;
        bf16x8 a = __builtin_bit_cast(bf16x8, B[g * 32 + (ln ^ (g & 7))]);
        acc = __builtin_amdgcn_mfma_f32_32x32x16_bf16(
            a, __builtin_bit_cast(bf16x8, areg[j]), acc, 0, 0, 0);
      }

      // lane-local running top-2; n scan order monotone -> numpy ties
      int n0 = t * BN + 4 * kh;
#pragma unroll
      for (int r = 0; r < 16; ++r) {
        int n = n0 + (r & 3) + 8 * (r >> 2);
        float v = acc[r];
        if (v > v1) { v2 = v1; i2 = i1; v1 = v; i1 = n; }
        else if (v > v2) { v2 = v; i2 = n; }
      }

      if (hn) {  // convert + write next buffer
        float sq = dot4(f0) + dot4(f1) + dot4(f2) + dot4(f3);
        sq += __shfl_xor(sq, 1); sq += __shfl_xor(sq, 2);
        sq += __shfl_xor(sq, 4); sq += __shfl_xor(sq, 8);
        float rs = 1.0f / fmaxf(sqrtf(sq), 1e-8f);
        uint2* B2 = (uint2*)&Bs[cur ^ 1][0];
        B2[(g0i * 32 + (row ^ (g0i & 7))) * 2 + h] =
            make_uint2(pk(f0.x * rs, f0.y * rs), pk(f0.z * rs, f0.w * rs));
        int ga = 8 + g0i;
        B2[(ga * 32 + (row ^ (ga & 7))) * 2 + h] =
            make_uint2(pk(f1.x * rs, f1.y * rs), pk(f1.z * rs, f1.w * rs));
        int gb = 16 + g0i;
        B2[(gb * 32 + (row ^ (gb & 7))) * 2 + h] =
            make_uint2(pk(f2.x * rs, f2.y * rs), pk(f2.z * rs, f2.w * rs));
        if (extra)
          B2[(24 * 32 + row) * 2 + part] =
              make_uint2(pk(f3.x * rs, f3.y * rs), pk(f3.z * rs, f3.w * rs));
      }
      __syncthreads();
      cur ^= 1;
    }

    // merge the two kh halves (same bm, disjoint n)
    float w1 = __shfl_xor(v1, 32); int j1 = __shfl_xor(i1, 32);
    float w2 = __shfl_xor(v2, 32); int j2 = __shfl_xor(i2, 32);
    float o1, o2; int oi1, oi2;
    if (better(w1, j1, v1, i1)) {
      bool tt = better(v1, i1, w2, j2);
      o1 = w1; oi1 = j1; o2 = tt ? v1 : w2; oi2 = tt ? i1 : j2;
    } else {
      bool tt = better(w1, j1, v2, i2);
      o1 = v1; oi1 = i1; o2 = tt ? w1 : v2; oi2 = tt ? j1 : i2;
    }
    if (kh == 0)
      partial[(size_t)bm * GRIDN + blockIdx.x] =
          make_float4(o1, __int_as_float(oi1), o2, __int_as_float(oi2));
  }

  __syncthreads();   // all partial stores of this block retired
  if (tid == 0)
    __hip_atomic_fetch_add(&ctr[1], 1, __ATOMIC_RELEASE,
                           __HIP_MEMORY_SCOPE_AGENT);
  if (blockIdx.x >= BB) return;

  // ================= Phase C: top-6 select + exact fp32 rescore ==========
  {
    int m = blockIdx.x;
    if (tid == 0) {
      while (__hip_atomic_load(&ctr[1], __ATOMIC_ACQUIRE,
                               __HIP_MEMORY_SCOPE_AGENT) < GRIDN)
        __builtin_amdgcn_s_sleep(2);
    }
    __syncthreads();

    if (tid < DD) repL[tid] = repf[m * DD + tid];
    const float4* pmp = partial + (size_t)m * GRIDN;
    float cv1 = -INFINITY, cv2 = -INFINITY;
    int ci1 = 0x7fffffff, ci2 = 0x7fffffff;
    {
      float4 E = pmp[tid];
      cv1 = E.x; ci1 = __float_as_int(E.y);
      cv2 = E.z; ci2 = __float_as_int(E.w);
    }
    __syncthreads();

    for (int r = 0; r < NCAND; ++r) {
      float bv = -INFINITY; int bi = 0x7fffffff;
      bool ex1 = false, ex2 = false;
      for (int j = 0; j < r; ++j) {
        int s = seln[j];
        ex1 |= (s == ci1); ex2 |= (s == ci2);
      }
      if (!ex1 && better(cv1, ci1, bv, bi)) { bv = cv1; bi = ci1; }
      if (!ex2 && better(cv2, ci2, bv, bi)) { bv = cv2; bi = ci2; }
#pragma unroll
      for (int off = 1; off < 64; off <<= 1) {
        float ov = __shfl_xor(bv, off); int oi = __shfl_xor(bi, off);
        if (better(ov, oi, bv, bi)) { bv = ov; bi = oi; }
      }
      if ((tid & 63) == 0) { wv[tid >> 6] = bv; wi[tid >> 6] = bi; }
      __syncthreads();
      if (tid == 0) {
        float Bv = wv[0]; int Bi = wi[0];
#pragma unroll
        for (int q = 1; q < 8; ++q)
          if (better(wv[q], wi[q], Bv, Bi)) { Bv = wv[q]; Bi = wi[q]; }
        seln[r] = Bi;
      }
      __syncthreads();
    }

    // exact fp32 rescore: one 64-lane wave per candidate
    int g = tid >> 6, lane = tid & 63;
    int n = (g < NCAND) ? seln[g] : -1;
    float s1 = 0.f, s2 = 0.f;
    if (n >= 0) {
      for (int d = lane; d < DD; d += 64) {
        float b = dict[(size_t)n * DD + d];
        s1 += repL[d] * b; s2 += b * b;
      }
    }
#pragma unroll
    for (int off = 1; off < 64; off <<= 1) {
      s1 += __shfl_xor(s1, off); s2 += __shfl_xor(s2, off);
    }
    if (lane == 0 && g < NCAND) {
      finv[g] = (n >= 0) ? s1 / fmaxf(mnorm[m] * sqrtf(s2), 1e-8f) : -INFINITY;
      finn[g] = n;
    }
    __syncthreads();
    if (tid == 0) {
      float Bv = finv[0]; int Bi = finn[0];
#pragma unroll
      for (int q = 1; q < NCAND; ++q)
        if (better(finv[q], finn[q], Bv, Bi)) { Bv = finv[q]; Bi = finn[q]; }
      out[m] = Bv;
      out[BB + m] = (float)Bi;  // indices as f32 (flat f32 readback)
    }
  }
}

extern "C" void kernel_launch(void* const* d_in, const int* in_sizes, int n_in,
                              void* d_out, int out_size, void* d_ws, size_t ws_size,
                              hipStream_t stream) {
  const int* ids = (const int*)d_in[0];
  const float* we = (const float*)d_in[1];
  const float* dict = (const float*)d_in[2];
  float* out = (float*)d_out;

  char* ws = (char*)d_ws;
  unsigned short* abf = (unsigned short*)ws;              // 28*256*16 = 114,688
  float* repf  = (float*)(ws + 114688);                   // 204,800
  float* mnorm = (float*)(ws + 319488);                   // 1,024
  float4* partial = (float4*)(ws + 320512);               // 256*512*16 = 2,097,152
  int* ctr = (int*)(ws + 2417664);                        // 2 counters

  hipMemsetAsync(ctr, 0, 2 * sizeof(int), stream);        // reset every replay
  fused_kernel<<<GRIDN, 512, 0, stream>>>(ids, we, dict, abf, repf, mnorm,
                                          partial, out, ctr);
}

// Round 11
// 45.919 us; speedup vs baseline: 2.9700x; 2.9700x over previous
//
#include <hip/hip_runtime.h>
#include <math.h>

#define BB 256
#define LL 8
#define DD 200
#define NN 100000
#define BN 32                        // concepts per tile (100000 % 32 == 0)
#define NTILE (NN / BN)              // 3125
#define NGRAN 28                     // 16B bf16 granules per row (K padded to 224)
#define GRID_SIM 512
#define NCAND 6

typedef __attribute__((ext_vector_type(8))) __bf16 bf16x8;
typedef __attribute__((ext_vector_type(16))) float f32x16;

// fp32 -> bf16 round-to-nearest-even
__device__ __forceinline__ unsigned f2bf(float x) {
  unsigned u = __float_as_uint(x);
  u = (u + 0x7fffu + ((u >> 16) & 1u)) >> 16;
  return u;
}
__device__ __forceinline__ unsigned pk(float a, float b) {
  return f2bf(a) | (f2bf(b) << 16);
}
// numpy argmax semantics: larger wins; exact tie -> smaller index
__device__ __forceinline__ bool better(float a, int ia, float b, int ib) {
  return (a > b) || (a == b && ia < ib);
}
__device__ __forceinline__ float dot4(float4 f) {
  return f.x * f.x + f.y * f.y + f.z * f.z + f.w * f.w;
}

// ------------- Kernel 1: mention rep (fp32 + bf16 granule-major) -------------
// abfT layout: uint4 unit index g*256 + m
__global__ __launch_bounds__(256) void prep_kernel(
    const int* __restrict__ ids, const float* __restrict__ we,
    float* __restrict__ repf, unsigned short* __restrict__ abf,
    float* __restrict__ mnorm) {
  int m = blockIdx.x, d = threadIdx.x;
  __shared__ float red[4];
  float r = 0.f;
  if (d < DD) {
    int base = m * LL;
#pragma unroll
    for (int l2 = 0; l2 < LL; ++l2) r += we[(size_t)ids[base + l2] * DD + d];
    r *= 0.125f;
    repf[m * DD + d] = r;
  }
  if (d < NGRAN * 8) {
    int g = d >> 3, wo = d & 7;
    abf[(g * 256 + m) * 8 + wo] = (unsigned short)f2bf(d < DD ? r : 0.f);
  }
  float sq = (d < DD) ? r * r : 0.f;
#pragma unroll
  for (int off = 32; off; off >>= 1) sq += __shfl_down(sq, off);
  if ((threadIdx.x & 63) == 0) red[threadIdx.x >> 6] = sq;
  __syncthreads();
  if (threadIdx.x == 0) mnorm[m] = sqrtf(red[0] + red[1] + red[2] + red[3]);
}

// ------------- Kernel 2: fused convert+MFMA sims -----------------------------
// NOTE launch bounds: plain (512), NO min-waves arg. R3 (lb(512)) gave
// VGPR=96 with areg resident; every (512,4) build let the allocator target
// 8 waves/EU (VGPR=64) and re-load areg from L2 every tile (R8-R10, 3x cost).
__global__ __launch_bounds__(512) void sim_kernel(
    const float* __restrict__ dict, const uint4* __restrict__ abfT,
    float4* __restrict__ partial) {
  __shared__ uint4 Bs[2][NGRAN * BN];   // 2 x 14 KB ring

  int tid = threadIdx.x;
  int w = tid >> 6, l = tid & 63;
  int ln = l & 31, kh = l >> 5;
  int m = w * 32 + ln;

  // mention fragments resident: granule 2j+kh for k-step j
  uint4 areg[14];
#pragma unroll
  for (int j = 0; j < 14; ++j) areg[j] = abfT[(2 * j + kh) * 256 + m];
#pragma unroll
  for (int j = 0; j < 14; ++j)
    asm volatile("" : "+v"(areg[j].x), "+v"(areg[j].y),
                      "+v"(areg[j].z), "+v"(areg[j].w));

  // staging role: 32 rows x 16 parts
  int row = tid >> 4, part = tid & 15;
  const bool extra = (part < 2);
  int g0i = part >> 1, h = part & 1;

  // zero-pad granules 25..27 (k 200..223) once, both buffers
  if (tid < 192) {
    int buf = tid / 96, u = tid % 96;
    int g = 25 + u / 32, r = u & 31;
    Bs[buf][g * 32 + (r ^ (g & 7))] = make_uint4(0, 0, 0, 0);
  }

  float v1 = -INFINITY, v2 = -INFINITY;
  int i1 = 0x7fffffff, i2 = 0x7fffffff;

  int t0 = blockIdx.x;
  // ---- prologue: stage tile t0 into buf 0 ----
  {
    const float* src = dict + (size_t)(t0 * BN + row) * DD;
    float4 f0 = *(const float4*)(src + 4 * part);
    float4 f1 = *(const float4*)(src + 64 + 4 * part);
    float4 f2 = *(const float4*)(src + 128 + 4 * part);
    float4 f3 = extra ? *(const float4*)(src + 192 + 4 * part)
                      : make_float4(0.f, 0.f, 0.f, 0.f);
    float sq = dot4(f0) + dot4(f1) + dot4(f2) + dot4(f3);
    sq += __shfl_xor(sq, 1); sq += __shfl_xor(sq, 2);
    sq += __shfl_xor(sq, 4); sq += __shfl_xor(sq, 8);
    float rs = 1.0f / fmaxf(sqrtf(sq), 1e-8f);
    uint2* B2 = (uint2*)&Bs[0][0];
    B2[(g0i * 32 + (row ^ (g0i & 7))) * 2 + h] =
        make_uint2(pk(f0.x * rs, f0.y * rs), pk(f0.z * rs, f0.w * rs));
    int ga = 8 + g0i;
    B2[(ga * 32 + (row ^ (ga & 7))) * 2 + h] =
        make_uint2(pk(f1.x * rs, f1.y * rs), pk(f1.z * rs, f1.w * rs));
    int gb = 16 + g0i;
    B2[(gb * 32 + (row ^ (gb & 7))) * 2 + h] =
        make_uint2(pk(f2.x * rs, f2.y * rs), pk(f2.z * rs, f2.w * rs));
    if (extra)
      B2[(24 * 32 + row) * 2 + part] =
          make_uint2(pk(f3.x * rs, f3.y * rs), pk(f3.z * rs, f3.w * rs));
  }
  __syncthreads();

  int cur = 0;
  for (int t = t0; t < NTILE; t += GRID_SIM) {
    bool hn = (t + GRID_SIM) < NTILE;
    float4 f0, f1, f2, f3;
    if (hn) {  // issue next tile's global loads early (hide under MFMA+scan)
      const float* src = dict + (size_t)((t + GRID_SIM) * BN + row) * DD;
      f0 = *(const float4*)(src + 4 * part);
      f1 = *(const float4*)(src + 64 + 4 * part);
      f2 = *(const float4*)(src + 128 + 4 * part);
      f3 = extra ? *(const float4*)(src + 192 + 4 * part)
                 : make_float4(0.f, 0.f, 0.f, 0.f);
    }
    __builtin_amdgcn_sched_barrier(0);   // keep loads issued here (no sinking)

    f32x16 acc;
#pragma unroll
    for (int i = 0; i < 16; ++i) acc[i] = 0.f;
    const uint4* B = Bs[cur];
#pragma unroll
    for (int j = 0; j < 14; ++j) {
      int g = 2 * j + kh;
      bf16x8 a = __builtin_bit_cast(bf16x8, B[g * 32 + (ln ^ (g & 7))]);
      acc = __builtin_amdgcn_mfma_f32_32x32x16_bf16(
          a, __builtin_bit_cast(bf16x8, areg[j]), acc, 0, 0, 0);
    }

    // lane-local running top-2; n scan order monotone -> numpy tie semantics
    int n0 = t * BN + 4 * kh;
#pragma unroll
    for (int r = 0; r < 16; ++r) {
      int n = n0 + (r & 3) + 8 * (r >> 2);
      float v = acc[r];
      if (v > v1) { v2 = v1; i2 = i1; v1 = v; i1 = n; }
      else if (v > v2) { v2 = v; i2 = n; }
    }

    if (hn) {  // convert + write next buffer (other waves no longer read it)
      float sq = dot4(f0) + dot4(f1) + dot4(f2) + dot4(f3);
      sq += __shfl_xor(sq, 1); sq += __shfl_xor(sq, 2);
      sq += __shfl_xor(sq, 4); sq += __shfl_xor(sq, 8);
      float rs = 1.0f / fmaxf(sqrtf(sq), 1e-8f);
      uint2* B2 = (uint2*)&Bs[cur ^ 1][0];
      B2[(g0i * 32 + (row ^ (g0i & 7))) * 2 + h] =
          make_uint2(pk(f0.x * rs, f0.y * rs), pk(f0.z * rs, f0.w * rs));
      int ga = 8 + g0i;
      B2[(ga * 32 + (row ^ (ga & 7))) * 2 + h] =
          make_uint2(pk(f1.x * rs, f1.y * rs), pk(f1.z * rs, f1.w * rs));
      int gb = 16 + g0i;
      B2[(gb * 32 + (row ^ (gb & 7))) * 2 + h] =
          make_uint2(pk(f2.x * rs, f2.y * rs), pk(f2.z * rs, f2.w * rs));
      if (extra)
        B2[(24 * 32 + row) * 2 + part] =
            make_uint2(pk(f3.x * rs, f3.y * rs), pk(f3.z * rs, f3.w * rs));
    }
    __syncthreads();   // publish writes; no vmem in flight here (drain free)
    cur ^= 1;
  }

  // merge the two kh halves (same m, disjoint n)
  float w1 = __shfl_xor(v1, 32); int j1 = __shfl_xor(i1, 32);
  float w2 = __shfl_xor(v2, 32); int j2 = __shfl_xor(i2, 32);
  float o1, o2; int oi1, oi2;
  if (better(w1, j1, v1, i1)) {
    bool tt = better(v1, i1, w2, j2);
    o1 = w1; oi1 = j1; o2 = tt ? v1 : w2; oi2 = tt ? i1 : j2;
  } else {
    bool tt = better(w1, j1, v2, i2);
    o1 = v1; oi1 = i1; o2 = tt ? w1 : v2; oi2 = tt ? j1 : i2;
  }
  if (kh == 0)
    partial[(size_t)m * GRID_SIM + blockIdx.x] =
        make_float4(o1, __int_as_float(oi1), o2, __int_as_float(oi2));
}

// ------------- Kernel 3: top-6 select + exact fp32 rescore -------------------
__global__ __launch_bounds__(256) void final_kernel(
    const float* __restrict__ dict, const float* __restrict__ repf,
    const float* __restrict__ mnorm, const float4* __restrict__ partial,
    float* __restrict__ out) {
  int m = blockIdx.x, tid = threadIdx.x;
  __shared__ float repL[DD];
  __shared__ int seln[NCAND];
  __shared__ float wv[4]; __shared__ int wi[4];
  __shared__ float finv[NCAND]; __shared__ int finn[NCAND];
  if (tid < DD) repL[tid] = repf[m * DD + tid];
  __syncthreads();

  const float4* pm = partial + (size_t)m * GRID_SIM;
  float cv1[2], cv2[2]; int ci1[2], ci2[2];
#pragma unroll
  for (int e = 0; e < 2; ++e) {
    float4 E = pm[tid + e * 256];
    cv1[e] = E.x; ci1[e] = __float_as_int(E.y);
    cv2[e] = E.z; ci2[e] = __float_as_int(E.w);
  }

  for (int r = 0; r < NCAND; ++r) {
    float bv = -INFINITY; int bi = 0x7fffffff;
#pragma unroll
    for (int e = 0; e < 2; ++e) {
      bool ex1 = false, ex2 = false;
      for (int j = 0; j < r; ++j) {
        int s = seln[j];
        ex1 |= (s == ci1[e]); ex2 |= (s == ci2[e]);
      }
      if (!ex1 && better(cv1[e], ci1[e], bv, bi)) { bv = cv1[e]; bi = ci1[e]; }
      if (!ex2 && better(cv2[e], ci2[e], bv, bi)) { bv = cv2[e]; bi = ci2[e]; }
    }
#pragma unroll
    for (int off = 1; off < 64; off <<= 1) {
      float ov = __shfl_xor(bv, off); int oi = __shfl_xor(bi, off);
      if (better(ov, oi, bv, bi)) { bv = ov; bi = oi; }
    }
    if ((tid & 63) == 0) { wv[tid >> 6] = bv; wi[tid >> 6] = bi; }
    __syncthreads();
    if (tid == 0) {
      float Bv = wv[0]; int Bi = wi[0];
#pragma unroll
      for (int q = 1; q < 4; ++q)
        if (better(wv[q], wi[q], Bv, Bi)) { Bv = wv[q]; Bi = wi[q]; }
      seln[r] = Bi;
    }
    __syncthreads();
  }

  // exact fp32 rescore: one 32-lane group per candidate
  int g = tid >> 5, lane = tid & 31;
  int n = (g < NCAND) ? seln[g] : -1;
  float s1 = 0.f, s2 = 0.f;
  if (n >= 0) {
    for (int d = lane; d < DD; d += 32) {
      float b = dict[(size_t)n * DD + d];
      s1 += repL[d] * b; s2 += b * b;
    }
  }
#pragma unroll
  for (int off = 1; off < 32; off <<= 1) {
    s1 += __shfl_xor(s1, off); s2 += __shfl_xor(s2, off);
  }
  if (lane == 0 && g < NCAND) {
    finv[g] = (n >= 0) ? s1 / fmaxf(mnorm[m] * sqrtf(s2), 1e-8f) : -INFINITY;
    finn[g] = n;
  }
  __syncthreads();
  if (tid == 0) {
    float Bv = finv[0]; int Bi = finn[0];
#pragma unroll
    for (int q = 1; q < NCAND; ++q)
      if (better(finv[q], finn[q], Bv, Bi)) { Bv = finv[q]; Bi = finn[q]; }
    out[m] = Bv;
    out[BB + m] = (float)Bi;  // indices as f32 (flat f32 readback)
  }
}

extern "C" void kernel_launch(void* const* d_in, const int* in_sizes, int n_in,
                              void* d_out, int out_size, void* d_ws, size_t ws_size,
                              hipStream_t stream) {
  const int* ids = (const int*)d_in[0];
  const float* we = (const float*)d_in[1];
  const float* dict = (const float*)d_in[2];
  float* out = (float*)d_out;

  char* ws = (char*)d_ws;
  unsigned short* abf = (unsigned short*)ws;              // 28*256*16 = 114,688
  float* repf  = (float*)(ws + 114688);                   // 204,800
  float* mnorm = (float*)(ws + 319488);                   // 1,024
  float4* partial = (float4*)(ws + 320512);               // 256*512*16 = 2,097,152

  prep_kernel<<<BB, 256, 0, stream>>>(ids, we, repf, abf, mnorm);
  sim_kernel<<<GRID_SIM, 512, 0, stream>>>(dict, (const uint4*)abf, partial);
  final_kernel<<<BB, 256, 0, stream>>>(dict, repf, mnorm, partial, out);
}